// Round 1
// baseline (324.032 us; speedup 1.0000x reference)
//
#include <hip/hip_runtime.h>

typedef __attribute__((ext_vector_type(8))) short bf16x8;
typedef __attribute__((ext_vector_type(4))) float f32x4;

static constexpr int HH = 224, WW = 224;
static constexpr int CIN = 64, HID = 64, COUT = 64;

__device__ __forceinline__ ushort f2bf(float f) {
    unsigned u = __builtin_bit_cast(unsigned, f);
    u += 0x7FFFu + ((u >> 16) & 1u);   // round-to-nearest-even
    return (ushort)(u >> 16);
}

// Tile: 8 rows x 32 cols of pixels per block; 4 waves, each wave = 64 px x 64 hid.
// K-order for conv GEMM: k = (dy, dx, c); chunk ch = dy*3+dx covers c 0..63 (2 MFMA k-steps).
__global__ __launch_bounds__(256, 2)
void mlpconv_kernel(const float* __restrict__ xin, const float* __restrict__ W1,
                    const float* __restrict__ b1, const float* __restrict__ W2,
                    const float* __restrict__ b2, float* __restrict__ out) {
    // LDS: 48,960 + 9,216 + 9,216 + 9,216 = 76,608 B -> 2 blocks/CU (160 KB LDS)
    __shared__ ushort xs[10 * 34 * 72];   // x tile bf16 [r][i][c pad 72]
    __shared__ ushort w1s[64 * 72];       // W1 chunk bf16 [n][c pad 72]
    __shared__ ushort w2s[64 * 72];       // W2 bf16 [o][k pad 72]
    __shared__ ushort hs[4 * 16 * 72];    // per-wave h scratch [m][k pad 72]

    const int tid = threadIdx.x;
    const int wave = tid >> 6;
    const int lane = tid & 63;
    const int l15 = lane & 15;
    const int quad = lane >> 4;

    const int x0 = blockIdx.x * 32;   // 7 tiles
    const int y0 = blockIdx.y * 8;    // 28 tiles
    const int b = blockIdx.z;         // 8 batches

    const float* xg = xin + (size_t)b * (CIN * HH * WW);

    // ---- stage x halo tile (10 rows x 34 cols x 64 ch), fp32 -> bf16, layout [r][i][c]
    for (int r = 0; r < 10; ++r) {
        const int gy = y0 + r - 1;
        const bool rowok = (unsigned)gy < (unsigned)HH;
        for (int e = tid; e < 544; e += 256) {   // 16 c-groups x 34 cols
            const int cg = e / 34;
            const int i = e - cg * 34;
            const int gx = x0 + i - 1;
            const bool ok = rowok && ((unsigned)gx < (unsigned)WW);
            const int c = cg * 4;
            float v0 = 0.f, v1 = 0.f, v2 = 0.f, v3 = 0.f;
            if (ok) {
                const float* p = xg + (c * HH + gy) * WW + gx;
                v0 = p[0]; v1 = p[HH * WW]; v2 = p[2 * HH * WW]; v3 = p[3 * HH * WW];
            }
            ushort4 pk = make_ushort4(f2bf(v0), f2bf(v1), f2bf(v2), f2bf(v3));
            *reinterpret_cast<ushort4*>(&xs[(r * 34 + i) * 72 + c]) = pk;
        }
    }
    // ---- stage W2 [o][k pad 72]
    for (int e = tid; e < 1024; e += 256) {
        const int o = e >> 4, g = e & 15, c = g * 4;
        const float4 v = *reinterpret_cast<const float4*>(W2 + o * 64 + c);
        ushort4 pk = make_ushort4(f2bf(v.x), f2bf(v.y), f2bf(v.z), f2bf(v.w));
        *reinterpret_cast<ushort4*>(&w2s[o * 72 + c]) = pk;
    }

    float b1v[4];
    #pragma unroll
    for (int nt = 0; nt < 4; ++nt) b1v[nt] = b1[nt * 16 + l15];

    f32x4 acc[4][4];   // [m-tile][n-tile]; C layout: col=lane&15 (=n), row=quad*4+reg (=m)
    #pragma unroll
    for (int mt = 0; mt < 4; ++mt)
        #pragma unroll
        for (int nt = 0; nt < 4; ++nt)
            acc[mt][nt] = (f32x4){b1v[nt], b1v[nt], b1v[nt], b1v[nt]};

    // ---- main loop: 9 (dy,dx) chunks, 2 k-steps of 32 channels each
    #pragma unroll
    for (int ch = 0; ch < 9; ++ch) {
        const int dy = ch / 3, dx = ch % 3;
        __syncthreads();
        // stage W1 chunk: w1s[n][c] = W1[n][c*9 + dy*3 + dx]
        for (int e = tid; e < 1024; e += 256) {
            const int n = e >> 4, g = e & 15, c = g * 4;
            const float* p = W1 + n * 576 + c * 9 + dy * 3 + dx;
            ushort4 pk = make_ushort4(f2bf(p[0]), f2bf(p[9]), f2bf(p[18]), f2bf(p[27]));
            *reinterpret_cast<ushort4*>(&w1s[n * 72 + c]) = pk;
        }
        __syncthreads();
        #pragma unroll
        for (int s = 0; s < 2; ++s) {
            const int ko = s * 32 + quad * 8;
            bf16x8 bfr[4];
            #pragma unroll
            for (int nt = 0; nt < 4; ++nt)
                bfr[nt] = *reinterpret_cast<const bf16x8*>(&w1s[(nt * 16 + l15) * 72 + ko]);
            #pragma unroll
            for (int mt = 0; mt < 4; ++mt) {
                const int ry = 2 * wave + (mt >> 1);
                const int rx = (mt & 1) * 16 + l15;
                const bf16x8 afr = *reinterpret_cast<const bf16x8*>(
                    &xs[((ry + dy) * 34 + rx + dx) * 72 + ko]);
                #pragma unroll
                for (int nt = 0; nt < 4; ++nt)
                    acc[mt][nt] = __builtin_amdgcn_mfma_f32_16x16x32_bf16(
                        afr, bfr[nt], acc[mt][nt], 0, 0, 0);
            }
        }
    }

    // ---- epilogue: ReLU -> bf16 h (per-wave LDS) -> GEMM2 (A=W2, B=h^T) -> +b2 -> out
    float4 b2q[4];
    #pragma unroll
    for (int it = 0; it < 4; ++it)
        b2q[it] = *reinterpret_cast<const float4*>(b2 + it * 16 + quad * 4);

    ushort* myh = &hs[wave * (16 * 72)];
    float* outg = out + (size_t)b * (COUT * HH * WW);

    #pragma unroll
    for (int mt = 0; mt < 4; ++mt) {
        // write h tile (16 px x 64 hid), C-layout -> [m][k] LDS
        #pragma unroll
        for (int ni = 0; ni < 4; ++ni)
            #pragma unroll
            for (int r = 0; r < 4; ++r) {
                float v = acc[mt][ni][r];
                v = v > 0.f ? v : 0.f;
                myh[(quad * 4 + r) * 72 + ni * 16 + l15] = f2bf(v);
            }
        __syncthreads();
        f32x4 acc2[4];   // D2[o][m]: col=lane&15 (=m pixel), row=quad*4+reg (=o)
        #pragma unroll
        for (int it = 0; it < 4; ++it)
            acc2[it] = (f32x4){b2q[it].x, b2q[it].y, b2q[it].z, b2q[it].w};
        #pragma unroll
        for (int ks = 0; ks < 2; ++ks) {
            const bf16x8 hb = *reinterpret_cast<const bf16x8*>(
                &myh[l15 * 72 + ks * 32 + quad * 8]);          // B[k][m]: lane col = m
            #pragma unroll
            for (int it = 0; it < 4; ++it) {
                const bf16x8 wa = *reinterpret_cast<const bf16x8*>(
                    &w2s[(it * 16 + l15) * 72 + ks * 32 + quad * 8]);  // A[o][k]: lane row = o
                acc2[it] = __builtin_amdgcn_mfma_f32_16x16x32_bf16(wa, hb, acc2[it], 0, 0, 0);
            }
        }
        const int gy = y0 + 2 * wave + (mt >> 1);
        const int gx = x0 + (mt & 1) * 16 + l15;
        #pragma unroll
        for (int it = 0; it < 4; ++it)
            #pragma unroll
            for (int r = 0; r < 4; ++r) {
                const int o = it * 16 + quad * 4 + r;
                outg[(o * HH + gy) * WW + gx] = acc2[it][r];
            }
    }
}

extern "C" void kernel_launch(void* const* d_in, const int* in_sizes, int n_in,
                              void* d_out, int out_size, void* d_ws, size_t ws_size,
                              hipStream_t stream) {
    const float* x  = (const float*)d_in[0];
    const float* W1 = (const float*)d_in[1];
    const float* b1 = (const float*)d_in[2];
    const float* W2 = (const float*)d_in[3];
    const float* b2 = (const float*)d_in[4];
    float* out = (float*)d_out;
    dim3 grid(WW / 32, HH / 8, 8);   // (7, 28, 8) = 1568 blocks
    dim3 block(256);
    mlpconv_kernel<<<grid, block, 0, stream>>>(x, W1, b1, W2, b2, out);
}

// Round 2
// 288.354 us; speedup vs baseline: 1.1237x; 1.1237x over previous
//
#include <hip/hip_runtime.h>

typedef __attribute__((ext_vector_type(8))) short bf16x8;
typedef __attribute__((ext_vector_type(4))) float f32x4;

static constexpr int HH = 224, WW = 224;
static constexpr int CIN = 64;

__device__ __forceinline__ ushort f2bf(float f) {
    unsigned u = __builtin_bit_cast(unsigned, f);
    u += 0x7FFFu + ((u >> 16) & 1u);   // round-to-nearest-even
    return (ushort)(u >> 16);
}

// Reorder weights once per launch into ws: w1r[ch][n][c] bf16 (ch=dy*3+dx), w2r[o][c] bf16.
__global__ void prep_kernel(const float* __restrict__ W1, const float* __restrict__ W2,
                            ushort* __restrict__ w1r, ushort* __restrict__ w2r) {
    const int idx = blockIdx.x * 256 + threadIdx.x;
    if (idx < 36864) {
        const int ch = idx >> 12;
        const int n = (idx >> 6) & 63;
        const int c = idx & 63;
        w1r[idx] = f2bf(W1[n * 576 + c * 9 + ch]);
    } else if (idx < 40960) {
        const int j = idx - 36864;
        w2r[j] = f2bf(W2[j]);
    }
}

// Tile: 8 rows x 32 cols px / block; 4 waves x (64 px x 64 hid). K-order (dy,dx,c).
// Weights read straight from L2 (w1r/w2r identical for all blocks) -> no K-loop barriers.
__global__ __launch_bounds__(256, 3)
void mlpconv_kernel(const float* __restrict__ xin, const ushort* __restrict__ w1r,
                    const float* __restrict__ b1, const ushort* __restrict__ w2r,
                    const float* __restrict__ b2, float* __restrict__ out) {
    // 51,200 B -> 3 blocks/CU. Epilogue reuses xs as per-wave h-scratch.
    __shared__ ushort xs[10 * 40 * 64];

    const int tid = threadIdx.x;
    const int wave = tid >> 6;
    const int lane = tid & 63;
    const int l15 = lane & 15;
    const int quad = lane >> 4;

    const int x0 = blockIdx.x * 32;   // 7
    const int y0 = blockIdx.y * 8;    // 28
    const int b = blockIdx.z;         // 8

    const float* xg = xin + (size_t)b * (CIN * HH * WW);

    // ---- stage x: 10 rows x 40 px x 64 ch, fp32->bf16, XOR-swizzled [row][px][c^((px&7)*8)]
    // float4 along x; halo [x0-4, x0+36) is all-or-nothing valid per float4.
    for (int e = tid; e < 6400; e += 256) {
        const int i = e % 10;
        const int t = e / 10;
        const int c = t & 63;
        const int r = t >> 6;
        const int gy = y0 + r - 1;
        const int gx4 = x0 - 4 + i * 4;
        float4 v = make_float4(0.f, 0.f, 0.f, 0.f);
        if (((unsigned)gy < (unsigned)HH) && ((unsigned)gx4 <= 220u))
            v = *reinterpret_cast<const float4*>(xg + (c * HH + gy) * WW + gx4);
        const int p0 = r * 40 + i * 4;
        xs[(p0 + 0) * 64 + (c ^ (((p0 + 0) & 7) * 8))] = f2bf(v.x);
        xs[(p0 + 1) * 64 + (c ^ (((p0 + 1) & 7) * 8))] = f2bf(v.y);
        xs[(p0 + 2) * 64 + (c ^ (((p0 + 2) & 7) * 8))] = f2bf(v.z);
        xs[(p0 + 3) * 64 + (c ^ (((p0 + 3) & 7) * 8))] = f2bf(v.w);
    }

    float b1v[4];
    #pragma unroll
    for (int nt = 0; nt < 4; ++nt) b1v[nt] = b1[nt * 16 + l15];

    f32x4 acc[4][4];   // C layout: col=lane&15 (=n), row=quad*4+reg (=m)
    #pragma unroll
    for (int mt = 0; mt < 4; ++mt)
        #pragma unroll
        for (int nt = 0; nt < 4; ++nt)
            acc[mt][nt] = (f32x4){b1v[nt], b1v[nt], b1v[nt], b1v[nt]};

    __syncthreads();

    // ---- main loop: 18 k-steps (9 taps x 2 halves of 32 ch), barrier-free
    #pragma unroll 2
    for (int ks = 0; ks < 18; ++ks) {
        const int ch = ks >> 1;
        const int s = ks & 1;
        const int dy = ch / 3, dx = ch - 3 * (ch / 3);
        const int ko = s * 32 + quad * 8;
        bf16x8 bfr[4];
        #pragma unroll
        for (int nt = 0; nt < 4; ++nt)
            bfr[nt] = *reinterpret_cast<const bf16x8*>(
                w1r + ch * 4096 + (nt * 16 + l15) * 64 + ko);
        const int kswz = ko ^ (((l15 + dx + 3) & 7) * 8);
        #pragma unroll
        for (int mt = 0; mt < 4; ++mt) {
            const int row = 2 * wave + (mt >> 1) + dy;
            const int col = (mt & 1) * 16 + l15 + dx + 3;
            const bf16x8 afr = *reinterpret_cast<const bf16x8*>(
                &xs[(row * 40 + col) * 64 + kswz]);
            #pragma unroll
            for (int nt = 0; nt < 4; ++nt)
                acc[mt][nt] = __builtin_amdgcn_mfma_f32_16x16x32_bf16(
                    afr, bfr[nt], acc[mt][nt], 0, 0, 0);
        }
    }

    __syncthreads();   // other waves may still read xs; about to overwrite as h-scratch

    // ---- epilogue: ReLU -> bf16 h (per-wave LDS, no barrier) -> GEMM2 -> +b2 -> store
    float4 b2q[4];
    #pragma unroll
    for (int it = 0; it < 4; ++it)
        b2q[it] = *reinterpret_cast<const float4*>(b2 + it * 16 + quad * 4);

    bf16x8 wa2[2][4];   // W2 A-fragments, mt-invariant
    #pragma unroll
    for (int k2 = 0; k2 < 2; ++k2)
        #pragma unroll
        for (int it = 0; it < 4; ++it)
            wa2[k2][it] = *reinterpret_cast<const bf16x8*>(
                w2r + (it * 16 + l15) * 64 + k2 * 32 + quad * 8);

    ushort* myh = &xs[wave * (16 * 72)];
    float* outg = out + (size_t)b * (64 * HH * WW);

    #pragma unroll
    for (int mt = 0; mt < 4; ++mt) {
        #pragma unroll
        for (int ni = 0; ni < 4; ++ni)
            #pragma unroll
            for (int r = 0; r < 4; ++r) {
                float v = acc[mt][ni][r];
                v = v > 0.f ? v : 0.f;
                myh[(quad * 4 + r) * 72 + ni * 16 + l15] = f2bf(v);
            }
        f32x4 acc2[4];   // D2: col=lane&15 (=px), row=quad*4+reg (=cout)
        #pragma unroll
        for (int it = 0; it < 4; ++it)
            acc2[it] = (f32x4){b2q[it].x, b2q[it].y, b2q[it].z, b2q[it].w};
        #pragma unroll
        for (int k2 = 0; k2 < 2; ++k2) {
            const bf16x8 hb = *reinterpret_cast<const bf16x8*>(
                &myh[l15 * 72 + k2 * 32 + quad * 8]);
            #pragma unroll
            for (int it = 0; it < 4; ++it)
                acc2[it] = __builtin_amdgcn_mfma_f32_16x16x32_bf16(
                    wa2[k2][it], hb, acc2[it], 0, 0, 0);
        }
        const int gy = y0 + 2 * wave + (mt >> 1);
        const int gx = x0 + (mt & 1) * 16 + l15;
        #pragma unroll
        for (int it = 0; it < 4; ++it)
            #pragma unroll
            for (int r = 0; r < 4; ++r) {
                const int o = it * 16 + quad * 4 + r;
                outg[(o * HH + gy) * WW + gx] = acc2[it][r];
            }
    }
}

extern "C" void kernel_launch(void* const* d_in, const int* in_sizes, int n_in,
                              void* d_out, int out_size, void* d_ws, size_t ws_size,
                              hipStream_t stream) {
    const float* x  = (const float*)d_in[0];
    const float* W1 = (const float*)d_in[1];
    const float* b1 = (const float*)d_in[2];
    const float* W2 = (const float*)d_in[3];
    const float* b2 = (const float*)d_in[4];
    float* out = (float*)d_out;

    ushort* w1r = (ushort*)d_ws;             // 9*64*64 bf16 = 73,728 B
    ushort* w2r = w1r + 9 * 64 * 64;         // 64*64 bf16 = 8,192 B

    prep_kernel<<<160, 256, 0, stream>>>(W1, W2, w1r, w2r);
    dim3 grid(WW / 32, HH / 8, 8);           // (7, 28, 8)
    mlpconv_kernel<<<grid, dim3(256), 0, stream>>>(x, w1r, b1, w2r, b2, out);
}